// Round 15
// baseline (273.432 us; speedup 1.0000x reference)
//
#include <hip/hip_runtime.h>
#include <hip/hip_bf16.h>

#define BATCH 8192
#define DMODEL 4096
#define NEXP 64

typedef __attribute__((ext_vector_type(8))) short short8;   // 8 bf16 (4 VGPR)
typedef __attribute__((ext_vector_type(4))) float f32x4;

#define WF_FLOATS  393216   // 786432 ushorts = 128 ksteps * 6144

// direct global->LDS async copy, 16B per lane; LDS dest = wave-uniform base + lane*16
#define GLD16(dst_lds, src_g)                                                  \
    __builtin_amdgcn_global_load_lds(                                          \
        (const __attribute__((address_space(1))) void*)(src_g),                \
        (__attribute__((address_space(3))) void*)(dst_lds), 16, 0, 0)

// ============================================================================
// Build W planes (h/m/l bf16 split), per-kstep contiguous:
// WF2[ks][plane][cf][lane][j] <- split of W[e=cf*16+(l&15)][k=ks*32+(l>>4)*8+j]
// ============================================================================
__global__ __launch_bounds__(256) void build_wf(const float* __restrict__ W,
                                                unsigned short* __restrict__ WF2)
{
    const int gid = blockIdx.x * 256 + threadIdx.x;   // 0..32767
    const int ks = gid >> 8;
    const int cf = (gid >> 6) & 3;
    const int l  = gid & 63;
    const int e  = cf * 16 + (l & 15);
    const int k0 = ks * 32 + (l >> 4) * 8;
    const float* src = W + (size_t)e * DMODEL + k0;

    short8 hv, mv, lv;
#pragma unroll
    for (int j = 0; j < 8; ++j) {
        const float xv = src[j];
        const __hip_bfloat16 h = __float2bfloat16(xv);
        const float r1 = xv - __bfloat162float(h);
        const __hip_bfloat16 m = __float2bfloat16(r1);
        const float r2 = r1 - __bfloat162float(m);
        const __hip_bfloat16 lo = __float2bfloat16(r2);
        hv[j] = (short)__builtin_bit_cast(unsigned short, h);
        mv[j] = (short)__builtin_bit_cast(unsigned short, m);
        lv[j] = (short)__builtin_bit_cast(unsigned short, lo);
    }
    const size_t base = (size_t)ks * 6144 + cf * 512 + l * 8;
    *(short8*)&WF2[base]        = hv;
    *(short8*)&WF2[base + 2048] = mv;
    *(short8*)&WF2[base + 4096] = lv;
}

// ============================================================================
// MFMA GEMM (r9-proven, byte-identical): 256 threads (4 waves), 64x64 tile,
// BK=32, global_load_lds staging, double-buffered LDS, counted vmcnt(5).
// ============================================================================

#define CVT1(V, J, AH, AM, AL) {                                              \
    const float xv_ = (V);                                                    \
    const __hip_bfloat16 h_ = __float2bfloat16(xv_);                          \
    const float r1_ = xv_ - __bfloat162float(h_);                             \
    const __hip_bfloat16 m_ = __float2bfloat16(r1_);                          \
    const float r2_ = r1_ - __bfloat162float(m_);                             \
    const __hip_bfloat16 l_ = __float2bfloat16(r2_);                          \
    AH[J] = (short)__builtin_bit_cast(unsigned short, h_);                    \
    AM[J] = (short)__builtin_bit_cast(unsigned short, m_);                    \
    AL[J] = (short)__builtin_bit_cast(unsigned short, l_); }

#define CVT8(X0, X1, AH, AM, AL)                                              \
    CVT1(X0[0], 0, AH, AM, AL) CVT1(X0[1], 1, AH, AM, AL)                     \
    CVT1(X0[2], 2, AH, AM, AL) CVT1(X0[3], 3, AH, AM, AL)                     \
    CVT1(X1[0], 4, AH, AM, AL) CVT1(X1[1], 5, AH, AM, AL)                     \
    CVT1(X1[2], 6, AH, AM, AL) CVT1(X1[3], 7, AH, AM, AL)

#define MFMA(A, B, C) __builtin_amdgcn_mfma_f32_16x16x32_bf16(A, B, C, 0, 0, 0)

__global__ __launch_bounds__(256, 4) void gemm_mfma(const float* __restrict__ x,
                                                    const unsigned short* __restrict__ WF2,
                                                    float* __restrict__ part,
                                                    int S)
{
    __shared__ float xs[2][2048];            // A tiles: [buf][64 rows * 32 k], 8 KB each
    __shared__ unsigned short wsh[2][6144];  // B tiles: [buf][3 planes][4 cf][64][8], 12 KB each

    const int t = threadIdx.x;
    const int l = t & 63;
    const int wid = t >> 6;
    const int g = blockIdx.x & 127;          // row group (64 rows)
    const int s = blockIdx.x >> 7;           // k-split
    const int rowbase = g * 64;
    const int kbeg = s * (DMODEL / S);
    const int nsteps = (DMODEL / S) >> 5;    // 32-k steps

    const float* pxa[2];
#pragma unroll
    for (int r = 0; r < 2; ++r) {
        const int tr = wid * 16 + r * 8 + (l >> 3);
        const int ul = (l & 7) ^ (tr & 7);
        pxa[r] = x + (size_t)(rowbase + tr) * DMODEL + kbeg + ul * 4;
    }
    const unsigned short* pwb = WF2 + (size_t)(kbeg >> 5) * 6144 + t * 8;

#define STAGE(BUF, IT) {                                                       \
    _Pragma("unroll")                                                          \
    for (int r_ = 0; r_ < 2; ++r_)                                             \
        GLD16(&xs[BUF][wid * 512 + r_ * 256], pxa[r_] + (size_t)(IT) * 32);    \
    _Pragma("unroll")                                                          \
    for (int r_ = 0; r_ < 3; ++r_)                                             \
        GLD16(&wsh[BUF][r_ * 2048 + wid * 512],                                \
              pwb + (size_t)(IT) * 6144 + r_ * 2048); }

    const int lr = l & 15;
    const int lk = l >> 4;
    const int xr = lr & 7;
    const int trw = wid * 16 + lr;
    const int a0 = trw * 32 + (((lk * 2)     ^ xr) * 4);
    const int a1 = trw * 32 + (((lk * 2 + 1) ^ xr) * 4);

    f32x4 acc[4] = {};

    STAGE(0, 0)

    for (int it = 0; it < nsteps; ++it) {
        const int cur = it & 1;
        if (it + 1 < nsteps) {
            STAGE(cur ^ 1, it + 1)
            asm volatile("s_waitcnt vmcnt(5)" ::: "memory");
        } else {
            asm volatile("s_waitcnt vmcnt(0)" ::: "memory");
        }
        __builtin_amdgcn_s_barrier();

        const f32x4 xa0 = *(const f32x4*)&xs[cur][a0];
        const f32x4 xa1 = *(const f32x4*)&xs[cur][a1];
        short8 ah, am, al;
        CVT8(xa0, xa1, ah, am, al)

#pragma unroll
        for (int cf = 0; cf < 4; ++cf) {
            const unsigned short* wp = &wsh[cur][cf * 512 + l * 8];
            const short8 bh = *(const short8*)(wp);
            const short8 bm = *(const short8*)(wp + 2048);
            const short8 bl = *(const short8*)(wp + 4096);
            acc[cf] = MFMA(ah, bh, acc[cf]);
            acc[cf] = MFMA(ah, bm, acc[cf]);
            acc[cf] = MFMA(am, bh, acc[cf]);
            acc[cf] = MFMA(ah, bl, acc[cf]);
            acc[cf] = MFMA(al, bh, acc[cf]);
            acc[cf] = MFMA(am, bm, acc[cf]);
        }
        __builtin_amdgcn_s_barrier();
    }

    const int orow = lk * 4;
#pragma unroll
    for (int j = 0; j < 4; ++j) {
        const int row = rowbase + wid * 16 + orow + j;
        float* dst = part + ((size_t)s * BATCH + row) * NEXP + lr;
#pragma unroll
        for (int cf = 0; cf < 4; ++cf)
            dst[cf * 16] = acc[cf][j];
    }
#undef STAGE
}

// ============================================================================
// Router (r9-proven): sum S partials -> logits; top-2 + softmax weights;
// atomicAdd accumulation; LAST block computes the loss (fused).
// ============================================================================
template<int NS>
__global__ __launch_bounds__(256) void router2(const float* __restrict__ part,
                                               const float* __restrict__ noise,
                                               float* __restrict__ out,
                                               float* __restrict__ probsum,
                                               float* __restrict__ counts,
                                               int* __restrict__ done)
{
    __shared__ float sps[4][64];
    __shared__ float scnt[4][64];
    __shared__ int lastFlag;

    const int t = threadIdx.x;
    const int w = t >> 6;
    const int lane = t & 63;
    const int wg = blockIdx.x * 4 + w;   // 0..1023

    float* out_idx = out;
    float* out_w = out + 16384;
    float* out_logits = out + 32768;

    float psum_local = 0.f;
    float cnt_local = 0.f;

    for (int r = 0; r < 8; ++r) {
        const int row = wg * 8 + r;
        float lgt = 0.f;
#pragma unroll
        for (int s = 0; s < NS; ++s)
            lgt += part[((size_t)s * BATCH + row) * NEXP + lane];
        out_logits[(size_t)row * NEXP + lane] = lgt;

        const float ny = lgt + 0.1f * noise[(size_t)row * NEXP + lane];

        float v1 = ny; int i1 = lane;
#pragma unroll
        for (int m = 32; m >= 1; m >>= 1) {
            float ov = __shfl_xor(v1, m);
            int oi = __shfl_xor(i1, m);
            if (ov > v1 || (ov == v1 && oi < i1)) { v1 = ov; i1 = oi; }
        }
        float v2 = (lane == i1) ? -1e30f : ny; int i2 = lane;
#pragma unroll
        for (int m = 32; m >= 1; m >>= 1) {
            float ov = __shfl_xor(v2, m);
            int oi = __shfl_xor(i2, m);
            if (ov > v2 || (ov == v2 && oi < i2)) { v2 = ov; i2 = oi; }
        }

        if (lane == 0) {
            const float d = expf(v2 - v1);
            const float w1 = 1.0f / (1.0f + d);
            out_idx[row * 2 + 0] = (float)i1;
            out_idx[row * 2 + 1] = (float)i2;
            out_w[row * 2 + 0] = w1;
            out_w[row * 2 + 1] = 1.0f - w1;
        }

        float m = lgt;
#pragma unroll
        for (int ss = 32; ss >= 1; ss >>= 1) m = fmaxf(m, __shfl_xor(m, ss));
        const float p = expf(lgt - m);
        float sum = p;
#pragma unroll
        for (int ss = 32; ss >= 1; ss >>= 1) sum += __shfl_xor(sum, ss);
        psum_local += p / sum;
        cnt_local += (lane == i1 ? 1.f : 0.f) + (lane == i2 ? 1.f : 0.f);
    }

    sps[w][lane] = psum_local;
    scnt[w][lane] = cnt_local;
    __syncthreads();
    if (t < 64) {
        float ssum = 0.f, c = 0.f;
#pragma unroll
        for (int ww = 0; ww < 4; ++ww) { ssum += sps[ww][t]; c += scnt[ww][t]; }
        atomicAdd(&probsum[t], ssum);
        atomicAdd(&counts[t], c);
    }
    __syncthreads();
    if (t == 0) {
        __threadfence();
        lastFlag = (atomicAdd(done, 1) == (int)gridDim.x - 1) ? 1 : 0;
    }
    __syncthreads();
    if (lastFlag && t < 64) {
        const float ps = __hip_atomic_load(&probsum[t], __ATOMIC_RELAXED,
                                           __HIP_MEMORY_SCOPE_AGENT);
        const float ct = __hip_atomic_load(&counts[t], __ATOMIC_RELAXED,
                                           __HIP_MEMORY_SCOPE_AGENT);
        float v = ps * ct;
#pragma unroll
        for (int ss = 32; ss >= 1; ss >>= 1) v += __shfl_xor(v, ss);
        if (t == 0)
            out[557056] = (float)NEXP * v / ((float)BATCH * (float)BATCH);
    }
}

// ============================================================================
// MEASUREMENT ROUND: r9 baseline + gemm x8 (idempotent). G = (dur - 64.4)/7.
// Purpose: the rocprof top-5 (currently all 75us harness fills) becomes
// gemm_mfma dispatches with real counters -> pick the next-fix branch.
// ============================================================================
extern "C" void kernel_launch(void* const* d_in, const int* in_sizes, int n_in,
                              void* d_out, int out_size, void* d_ws, size_t ws_size,
                              hipStream_t stream)
{
    const float* x = (const float*)d_in[0];
    const float* W = (const float*)d_in[1];
    const float* noise = (const float*)d_in[2];
    float* out = (float*)d_out;
    float* ws = (float*)d_ws;

    float* probsum = ws;                                   // 64 floats
    float* counts = ws + 64;                               // 64 floats
    int* done = (int*)(ws + 128);                          // 1 int
    unsigned short* WF2 = (unsigned short*)(ws + 256);     // 1.5 MB
    float* part = ws + 256 + WF_FLOATS;                    // S * 8192 * 64 floats

    int S = 1;
    const size_t base_floats = 256 + WF_FLOATS;
    for (int cand = 8; cand >= 1; cand >>= 1) {
        const size_t need = (base_floats + (size_t)cand * BATCH * NEXP) * sizeof(float);
        if (ws_size >= need) { S = cand; break; }
    }

    hipMemsetAsync(d_ws, 0, 1024, stream);

    build_wf<<<128, 256, 0, stream>>>(W, WF2);

    for (int rep = 0; rep < 8; ++rep)
        gemm_mfma<<<128 * S, 256, 0, stream>>>(x, WF2, part, S);

    switch (S) {
        case 8: router2<8><<<256, 256, 0, stream>>>(part, noise, out, probsum, counts, done); break;
        case 4: router2<4><<<256, 256, 0, stream>>>(part, noise, out, probsum, counts, done); break;
        case 2: router2<2><<<256, 256, 0, stream>>>(part, noise, out, probsum, counts, done); break;
        default: router2<1><<<256, 256, 0, stream>>>(part, noise, out, probsum, counts, done); break;
    }
}

// Round 16
// 203.401 us; speedup vs baseline: 1.3443x; 1.3443x over previous
//
#include <hip/hip_runtime.h>
#include <hip/hip_bf16.h>

#define BATCH 8192
#define DMODEL 4096
#define NEXP 64

typedef __attribute__((ext_vector_type(8))) short short8;   // 8 bf16 (4 VGPR)
typedef __attribute__((ext_vector_type(4))) float f32x4;

#define WF_FLOATS  393216   // 786432 ushorts = 128 ksteps * 6144

// direct global->LDS async copy, 16B per lane; LDS dest = wave-uniform base + lane*16
#define GLD16(dst_lds, src_g)                                                  \
    __builtin_amdgcn_global_load_lds(                                          \
        (const __attribute__((address_space(1))) void*)(src_g),                \
        (__attribute__((address_space(3))) void*)(dst_lds), 16, 0, 0)

// ============================================================================
// Build W planes (h/m/l bf16 split) + zero the accumulator region (fused memset)
// ============================================================================
__global__ __launch_bounds__(256) void build_wf(const float* __restrict__ W,
                                                unsigned short* __restrict__ WF2,
                                                float* __restrict__ zbase)
{
    const int t = threadIdx.x;
    if (blockIdx.x == 0) {           // zero ws[0..511]: probsum/counts/done/gcnt
        zbase[t] = 0.f;
        zbase[t + 256] = 0.f;
    }

    const int gid = blockIdx.x * 256 + t;             // 0..32767
    const int ks = gid >> 8;
    const int cf = (gid >> 6) & 3;
    const int l  = gid & 63;
    const int e  = cf * 16 + (l & 15);
    const int k0 = ks * 32 + (l >> 4) * 8;
    const float* src = W + (size_t)e * DMODEL + k0;

    short8 hv, mv, lv;
#pragma unroll
    for (int j = 0; j < 8; ++j) {
        const float xv = src[j];
        const __hip_bfloat16 h = __float2bfloat16(xv);
        const float r1 = xv - __bfloat162float(h);
        const __hip_bfloat16 m = __float2bfloat16(r1);
        const float r2 = r1 - __bfloat162float(m);
        const __hip_bfloat16 lo = __float2bfloat16(r2);
        hv[j] = (short)__builtin_bit_cast(unsigned short, h);
        mv[j] = (short)__builtin_bit_cast(unsigned short, m);
        lv[j] = (short)__builtin_bit_cast(unsigned short, lo);
    }
    const size_t base = (size_t)ks * 6144 + cf * 512 + l * 8;
    *(short8*)&WF2[base]        = hv;
    *(short8*)&WF2[base + 2048] = mv;
    *(short8*)&WF2[base + 4096] = lv;
}

// ============================================================================
// Fused GEMM + router: r9-proven gemm (4 waves, 64x64 tile, BK=32,
// global_load_lds dbuf, counted vmcnt(5)); per-row-group done-counter
// handshake; 8th finisher routes its group's 64 rows; loss via done counter.
// ============================================================================

#define CVT1(V, J, AH, AM, AL) {                                              \
    const float xv_ = (V);                                                    \
    const __hip_bfloat16 h_ = __float2bfloat16(xv_);                          \
    const float r1_ = xv_ - __bfloat162float(h_);                             \
    const __hip_bfloat16 m_ = __float2bfloat16(r1_);                          \
    const float r2_ = r1_ - __bfloat162float(m_);                             \
    const __hip_bfloat16 l_ = __float2bfloat16(r2_);                          \
    AH[J] = (short)__builtin_bit_cast(unsigned short, h_);                    \
    AM[J] = (short)__builtin_bit_cast(unsigned short, m_);                    \
    AL[J] = (short)__builtin_bit_cast(unsigned short, l_); }

#define CVT8(X0, X1, AH, AM, AL)                                              \
    CVT1(X0[0], 0, AH, AM, AL) CVT1(X0[1], 1, AH, AM, AL)                     \
    CVT1(X0[2], 2, AH, AM, AL) CVT1(X0[3], 3, AH, AM, AL)                     \
    CVT1(X1[0], 4, AH, AM, AL) CVT1(X1[1], 5, AH, AM, AL)                     \
    CVT1(X1[2], 6, AH, AM, AL) CVT1(X1[3], 7, AH, AM, AL)

#define MFMA(A, B, C) __builtin_amdgcn_mfma_f32_16x16x32_bf16(A, B, C, 0, 0, 0)

template<int NS>
__global__ __launch_bounds__(256, 4) void gemm_fused(const float* __restrict__ x,
                                                     const unsigned short* __restrict__ WF2,
                                                     float* __restrict__ part,
                                                     const float* __restrict__ noise,
                                                     float* __restrict__ out,
                                                     float* __restrict__ probsum,
                                                     float* __restrict__ counts,
                                                     int* __restrict__ gcnt,
                                                     int* __restrict__ done)
{
    __shared__ float xs[2][2048];            // A tiles, 8 KB each
    __shared__ unsigned short wsh[2][6144];  // B tiles, 12 KB each
    __shared__ int routeFlag, lastFlag;

    const int t = threadIdx.x;
    const int l = t & 63;
    const int wid = t >> 6;
    const int g = blockIdx.x & 127;          // row group (64 rows)
    const int s = blockIdx.x >> 7;           // k-split
    const int rowbase = g * 64;
    const int kbeg = s * (DMODEL / NS);
    const int nsteps = (DMODEL / NS) >> 5;

    const float* pxa[2];
#pragma unroll
    for (int r = 0; r < 2; ++r) {
        const int tr = wid * 16 + r * 8 + (l >> 3);
        const int ul = (l & 7) ^ (tr & 7);
        pxa[r] = x + (size_t)(rowbase + tr) * DMODEL + kbeg + ul * 4;
    }
    const unsigned short* pwb = WF2 + (size_t)(kbeg >> 5) * 6144 + t * 8;

#define STAGE(BUF, IT) {                                                       \
    _Pragma("unroll")                                                          \
    for (int r_ = 0; r_ < 2; ++r_)                                             \
        GLD16(&xs[BUF][wid * 512 + r_ * 256], pxa[r_] + (size_t)(IT) * 32);    \
    _Pragma("unroll")                                                          \
    for (int r_ = 0; r_ < 3; ++r_)                                             \
        GLD16(&wsh[BUF][r_ * 2048 + wid * 512],                                \
              pwb + (size_t)(IT) * 6144 + r_ * 2048); }

    const int lr = l & 15;
    const int lk = l >> 4;
    const int xr = lr & 7;
    const int trw = wid * 16 + lr;
    const int a0 = trw * 32 + (((lk * 2)     ^ xr) * 4);
    const int a1 = trw * 32 + (((lk * 2 + 1) ^ xr) * 4);

    f32x4 acc[4] = {};

    STAGE(0, 0)

    for (int it = 0; it < nsteps; ++it) {
        const int cur = it & 1;
        if (it + 1 < nsteps) {
            STAGE(cur ^ 1, it + 1)
            asm volatile("s_waitcnt vmcnt(5)" ::: "memory");
        } else {
            asm volatile("s_waitcnt vmcnt(0)" ::: "memory");
        }
        __builtin_amdgcn_s_barrier();

        const f32x4 xa0 = *(const f32x4*)&xs[cur][a0];
        const f32x4 xa1 = *(const f32x4*)&xs[cur][a1];
        short8 ah, am, al;
        CVT8(xa0, xa1, ah, am, al)

#pragma unroll
        for (int cf = 0; cf < 4; ++cf) {
            const unsigned short* wp = &wsh[cur][cf * 512 + l * 8];
            const short8 bh = *(const short8*)(wp);
            const short8 bm = *(const short8*)(wp + 2048);
            const short8 bl = *(const short8*)(wp + 4096);
            acc[cf] = MFMA(ah, bh, acc[cf]);
            acc[cf] = MFMA(ah, bm, acc[cf]);
            acc[cf] = MFMA(am, bh, acc[cf]);
            acc[cf] = MFMA(ah, bl, acc[cf]);
            acc[cf] = MFMA(al, bh, acc[cf]);
            acc[cf] = MFMA(am, bm, acc[cf]);
        }
        __builtin_amdgcn_s_barrier();
    }

    const int orow = lk * 4;
#pragma unroll
    for (int j = 0; j < 4; ++j) {
        const int row = rowbase + wid * 16 + orow + j;
        float* dst = part + ((size_t)s * BATCH + row) * NEXP + lr;
#pragma unroll
        for (int cf = 0; cf < 4; ++cf)
            dst[cf * 16] = acc[cf][j];
    }
#undef STAGE

    // ---- per-group handshake: 8th finisher routes this group's 64 rows
    __threadfence();                      // release own part stores (device scope)
    __syncthreads();                      // all threads' fences done before count
    if (t == 0)
        routeFlag = (atomicAdd(&gcnt[g], 1) == NS - 1) ? 1 : 0;
    __syncthreads();
    if (!routeFlag) return;
    __threadfence();                      // acquire: see other splits' part stores

    // ================= routing phase (r9-proven body, 16 rows/wave) =========
    float* sps  = &xs[0][0];              // alias LDS (gemm done with it)
    float* scnt = &xs[0][256];

    float* out_idx = out;
    float* out_w = out + 16384;
    float* out_logits = out + 32768;

    float psum_local = 0.f;
    float cnt_local = 0.f;

    for (int r = 0; r < 16; ++r) {
        const int row = rowbase + wid * 16 + r;
        float lgt = 0.f;
#pragma unroll
        for (int ss = 0; ss < NS; ++ss)
            lgt += part[((size_t)ss * BATCH + row) * NEXP + l];
        out_logits[(size_t)row * NEXP + l] = lgt;

        const float ny = lgt + 0.1f * noise[(size_t)row * NEXP + l];

        float v1 = ny; int i1 = l;
#pragma unroll
        for (int m = 32; m >= 1; m >>= 1) {
            float ov = __shfl_xor(v1, m);
            int oi = __shfl_xor(i1, m);
            if (ov > v1 || (ov == v1 && oi < i1)) { v1 = ov; i1 = oi; }
        }
        float v2 = (l == i1) ? -1e30f : ny; int i2 = l;
#pragma unroll
        for (int m = 32; m >= 1; m >>= 1) {
            float ov = __shfl_xor(v2, m);
            int oi = __shfl_xor(i2, m);
            if (ov > v2 || (ov == v2 && oi < i2)) { v2 = ov; i2 = oi; }
        }

        if (l == 0) {
            const float d = expf(v2 - v1);
            const float w1 = 1.0f / (1.0f + d);
            out_idx[row * 2 + 0] = (float)i1;
            out_idx[row * 2 + 1] = (float)i2;
            out_w[row * 2 + 0] = w1;
            out_w[row * 2 + 1] = 1.0f - w1;
        }

        float m = lgt;
#pragma unroll
        for (int ss = 32; ss >= 1; ss >>= 1) m = fmaxf(m, __shfl_xor(m, ss));
        const float p = expf(lgt - m);
        float sum = p;
#pragma unroll
        for (int ss = 32; ss >= 1; ss >>= 1) sum += __shfl_xor(sum, ss);
        psum_local += p / sum;
        cnt_local += (l == i1 ? 1.f : 0.f) + (l == i2 ? 1.f : 0.f);
    }

    sps[wid * 64 + l] = psum_local;
    scnt[wid * 64 + l] = cnt_local;
    __syncthreads();
    if (t < 64) {
        float ssum = 0.f, c = 0.f;
#pragma unroll
        for (int ww = 0; ww < 4; ++ww) { ssum += sps[ww * 64 + t]; c += scnt[ww * 64 + t]; }
        atomicAdd(&probsum[t], ssum);
        atomicAdd(&counts[t], c);
    }
    __syncthreads();
    if (t == 0) {
        __threadfence();
        lastFlag = (atomicAdd(done, 1) == 127) ? 1 : 0;   // 128 routing blocks
    }
    __syncthreads();
    if (lastFlag && t < 64) {
        const float ps = __hip_atomic_load(&probsum[t], __ATOMIC_RELAXED,
                                           __HIP_MEMORY_SCOPE_AGENT);
        const float ct = __hip_atomic_load(&counts[t], __ATOMIC_RELAXED,
                                           __HIP_MEMORY_SCOPE_AGENT);
        float v = ps * ct;
#pragma unroll
        for (int ss = 32; ss >= 1; ss >>= 1) v += __shfl_xor(v, ss);
        if (t == 0)
            out[557056] = (float)NEXP * v / ((float)BATCH * (float)BATCH);
    }
}

// ============================================================================
extern "C" void kernel_launch(void* const* d_in, const int* in_sizes, int n_in,
                              void* d_out, int out_size, void* d_ws, size_t ws_size,
                              hipStream_t stream)
{
    const float* x = (const float*)d_in[0];
    const float* W = (const float*)d_in[1];
    const float* noise = (const float*)d_in[2];
    float* out = (float*)d_out;
    float* ws = (float*)d_ws;

    float* probsum = ws;                                   // 64 floats
    float* counts = ws + 64;                               // 64 floats
    int* done = (int*)(ws + 128);                          // 1 int
    int* gcnt = (int*)(ws + 192);                          // 128 ints
    unsigned short* WF2 = (unsigned short*)(ws + 512);     // 1.5 MB
    float* part = ws + 512 + WF_FLOATS;                    // S * 8192 * 64 floats

    int S = 1;
    const size_t base_floats = 512 + WF_FLOATS;
    for (int cand = 8; cand >= 1; cand >>= 1) {
        const size_t need = (base_floats + (size_t)cand * BATCH * NEXP) * sizeof(float);
        if (ws_size >= need) { S = cand; break; }
    }

    build_wf<<<128, 256, 0, stream>>>(W, WF2, ws);

    switch (S) {
        case 8: gemm_fused<8><<<128 * 8, 256, 0, stream>>>(x, WF2, part, noise, out, probsum, counts, gcnt, done); break;
        case 4: gemm_fused<4><<<128 * 4, 256, 0, stream>>>(x, WF2, part, noise, out, probsum, counts, gcnt, done); break;
        case 2: gemm_fused<2><<<128 * 2, 256, 0, stream>>>(x, WF2, part, noise, out, probsum, counts, gcnt, done); break;
        default: gemm_fused<1><<<128 * 1, 256, 0, stream>>>(x, WF2, part, noise, out, probsum, counts, gcnt, done); break;
    }
}

// Round 17
// 62.730 us; speedup vs baseline: 4.3589x; 3.2425x over previous
//
#include <hip/hip_runtime.h>
#include <hip/hip_bf16.h>

#define BATCH 8192
#define DMODEL 4096
#define NEXP 64

typedef __attribute__((ext_vector_type(8))) short short8;   // 8 bf16 (4 VGPR)
typedef __attribute__((ext_vector_type(4))) float f32x4;

#define WF_FLOATS  393216   // 786432 ushorts = 128 ksteps * 6144

// direct global->LDS async copy, 16B per lane; LDS dest = wave-uniform base + lane*16
#define GLD16(dst_lds, src_g)                                                  \
    __builtin_amdgcn_global_load_lds(                                          \
        (const __attribute__((address_space(1))) void*)(src_g),                \
        (__attribute__((address_space(3))) void*)(dst_lds), 16, 0, 0)

// ============================================================================
// Build W planes (h/m/l bf16 split), per-kstep contiguous; block 0 also zeroes
// the 2 KB accumulator region (replaces the hipMemsetAsync dispatch).
// ============================================================================
__global__ __launch_bounds__(256) void build_wf(const float* __restrict__ W,
                                                unsigned short* __restrict__ WF2,
                                                float* __restrict__ zbase)
{
    const int t = threadIdx.x;
    if (blockIdx.x == 0) {           // zero ws[0..511]: probsum/counts/done
        zbase[t] = 0.f;
        zbase[t + 256] = 0.f;
    }

    const int gid = blockIdx.x * 256 + t;             // 0..32767
    const int ks = gid >> 8;
    const int cf = (gid >> 6) & 3;
    const int l  = gid & 63;
    const int e  = cf * 16 + (l & 15);
    const int k0 = ks * 32 + (l >> 4) * 8;
    const float* src = W + (size_t)e * DMODEL + k0;

    short8 hv, mv, lv;
#pragma unroll
    for (int j = 0; j < 8; ++j) {
        const float xv = src[j];
        const __hip_bfloat16 h = __float2bfloat16(xv);
        const float r1 = xv - __bfloat162float(h);
        const __hip_bfloat16 m = __float2bfloat16(r1);
        const float r2 = r1 - __bfloat162float(m);
        const __hip_bfloat16 lo = __float2bfloat16(r2);
        hv[j] = (short)__builtin_bit_cast(unsigned short, h);
        mv[j] = (short)__builtin_bit_cast(unsigned short, m);
        lv[j] = (short)__builtin_bit_cast(unsigned short, lo);
    }
    const size_t base = (size_t)ks * 6144 + cf * 512 + l * 8;
    *(short8*)&WF2[base]        = hv;
    *(short8*)&WF2[base + 2048] = mv;
    *(short8*)&WF2[base + 4096] = lv;
}

// ============================================================================
// MFMA GEMM (r9-proven, byte-identical): 256 threads (4 waves), 64x64 tile,
// BK=32, global_load_lds staging, double-buffered LDS (exactly 40 KB ->
// 4 blocks/CU), counted vmcnt(5). NO shared flags (LDS budget!).
// ============================================================================

#define CVT1(V, J, AH, AM, AL) {                                              \
    const float xv_ = (V);                                                    \
    const __hip_bfloat16 h_ = __float2bfloat16(xv_);                          \
    const float r1_ = xv_ - __bfloat162float(h_);                             \
    const __hip_bfloat16 m_ = __float2bfloat16(r1_);                          \
    const float r2_ = r1_ - __bfloat162float(m_);                             \
    const __hip_bfloat16 l_ = __float2bfloat16(r2_);                          \
    AH[J] = (short)__builtin_bit_cast(unsigned short, h_);                    \
    AM[J] = (short)__builtin_bit_cast(unsigned short, m_);                    \
    AL[J] = (short)__builtin_bit_cast(unsigned short, l_); }

#define CVT8(X0, X1, AH, AM, AL)                                              \
    CVT1(X0[0], 0, AH, AM, AL) CVT1(X0[1], 1, AH, AM, AL)                     \
    CVT1(X0[2], 2, AH, AM, AL) CVT1(X0[3], 3, AH, AM, AL)                     \
    CVT1(X1[0], 4, AH, AM, AL) CVT1(X1[1], 5, AH, AM, AL)                     \
    CVT1(X1[2], 6, AH, AM, AL) CVT1(X1[3], 7, AH, AM, AL)

#define MFMA(A, B, C) __builtin_amdgcn_mfma_f32_16x16x32_bf16(A, B, C, 0, 0, 0)

__global__ __launch_bounds__(256, 4) void gemm_mfma(const float* __restrict__ x,
                                                    const unsigned short* __restrict__ WF2,
                                                    float* __restrict__ part,
                                                    int S)
{
    __shared__ float xs[2][2048];            // A tiles: [buf][64 rows * 32 k], 8 KB each
    __shared__ unsigned short wsh[2][6144];  // B tiles: [buf][3 planes][4 cf][64][8], 12 KB each

    const int t = threadIdx.x;
    const int l = t & 63;
    const int wid = t >> 6;
    const int g = blockIdx.x & 127;          // row group (64 rows)
    const int s = blockIdx.x >> 7;           // k-split
    const int rowbase = g * 64;
    const int kbeg = s * (DMODEL / S);
    const int nsteps = (DMODEL / S) >> 5;    // 32-k steps

    const float* pxa[2];
#pragma unroll
    for (int r = 0; r < 2; ++r) {
        const int tr = wid * 16 + r * 8 + (l >> 3);
        const int ul = (l & 7) ^ (tr & 7);
        pxa[r] = x + (size_t)(rowbase + tr) * DMODEL + kbeg + ul * 4;
    }
    const unsigned short* pwb = WF2 + (size_t)(kbeg >> 5) * 6144 + t * 8;

#define STAGE(BUF, IT) {                                                       \
    _Pragma("unroll")                                                          \
    for (int r_ = 0; r_ < 2; ++r_)                                             \
        GLD16(&xs[BUF][wid * 512 + r_ * 256], pxa[r_] + (size_t)(IT) * 32);    \
    _Pragma("unroll")                                                          \
    for (int r_ = 0; r_ < 3; ++r_)                                             \
        GLD16(&wsh[BUF][r_ * 2048 + wid * 512],                                \
              pwb + (size_t)(IT) * 6144 + r_ * 2048); }

    const int lr = l & 15;
    const int lk = l >> 4;
    const int xr = lr & 7;
    const int trw = wid * 16 + lr;
    const int a0 = trw * 32 + (((lk * 2)     ^ xr) * 4);
    const int a1 = trw * 32 + (((lk * 2 + 1) ^ xr) * 4);

    f32x4 acc[4] = {};

    STAGE(0, 0)

    for (int it = 0; it < nsteps; ++it) {
        const int cur = it & 1;
        if (it + 1 < nsteps) {
            STAGE(cur ^ 1, it + 1)
            asm volatile("s_waitcnt vmcnt(5)" ::: "memory");
        } else {
            asm volatile("s_waitcnt vmcnt(0)" ::: "memory");
        }
        __builtin_amdgcn_s_barrier();

        const f32x4 xa0 = *(const f32x4*)&xs[cur][a0];
        const f32x4 xa1 = *(const f32x4*)&xs[cur][a1];
        short8 ah, am, al;
        CVT8(xa0, xa1, ah, am, al)

#pragma unroll
        for (int cf = 0; cf < 4; ++cf) {
            const unsigned short* wp = &wsh[cur][cf * 512 + l * 8];
            const short8 bh = *(const short8*)(wp);
            const short8 bm = *(const short8*)(wp + 2048);
            const short8 bl = *(const short8*)(wp + 4096);
            acc[cf] = MFMA(ah, bh, acc[cf]);
            acc[cf] = MFMA(ah, bm, acc[cf]);
            acc[cf] = MFMA(am, bh, acc[cf]);
            acc[cf] = MFMA(ah, bl, acc[cf]);
            acc[cf] = MFMA(al, bh, acc[cf]);
            acc[cf] = MFMA(am, bm, acc[cf]);
        }
        __builtin_amdgcn_s_barrier();
    }

    const int orow = lk * 4;
#pragma unroll
    for (int j = 0; j < 4; ++j) {
        const int row = rowbase + wid * 16 + orow + j;
        float* dst = part + ((size_t)s * BATCH + row) * NEXP + lr;
#pragma unroll
        for (int cf = 0; cf < 4; ++cf)
            dst[cf * 16] = acc[cf][j];
    }
#undef STAGE
}

// ============================================================================
// Router (r9-proven): sum S partials -> logits; top-2 + softmax weights;
// atomicAdd accumulation; LAST block computes the loss (fused).
// ============================================================================
template<int NS>
__global__ __launch_bounds__(256) void router2(const float* __restrict__ part,
                                               const float* __restrict__ noise,
                                               float* __restrict__ out,
                                               float* __restrict__ probsum,
                                               float* __restrict__ counts,
                                               int* __restrict__ done)
{
    __shared__ float sps[4][64];
    __shared__ float scnt[4][64];
    __shared__ int lastFlag;

    const int t = threadIdx.x;
    const int w = t >> 6;
    const int lane = t & 63;
    const int wg = blockIdx.x * 4 + w;   // 0..1023

    float* out_idx = out;
    float* out_w = out + 16384;
    float* out_logits = out + 32768;

    float psum_local = 0.f;
    float cnt_local = 0.f;

    for (int r = 0; r < 8; ++r) {
        const int row = wg * 8 + r;
        float lgt = 0.f;
#pragma unroll
        for (int s = 0; s < NS; ++s)
            lgt += part[((size_t)s * BATCH + row) * NEXP + lane];
        out_logits[(size_t)row * NEXP + lane] = lgt;

        const float ny = lgt + 0.1f * noise[(size_t)row * NEXP + lane];

        float v1 = ny; int i1 = lane;
#pragma unroll
        for (int m = 32; m >= 1; m >>= 1) {
            float ov = __shfl_xor(v1, m);
            int oi = __shfl_xor(i1, m);
            if (ov > v1 || (ov == v1 && oi < i1)) { v1 = ov; i1 = oi; }
        }
        float v2 = (lane == i1) ? -1e30f : ny; int i2 = lane;
#pragma unroll
        for (int m = 32; m >= 1; m >>= 1) {
            float ov = __shfl_xor(v2, m);
            int oi = __shfl_xor(i2, m);
            if (ov > v2 || (ov == v2 && oi < i2)) { v2 = ov; i2 = oi; }
        }

        if (lane == 0) {
            const float d = expf(v2 - v1);
            const float w1 = 1.0f / (1.0f + d);
            out_idx[row * 2 + 0] = (float)i1;
            out_idx[row * 2 + 1] = (float)i2;
            out_w[row * 2 + 0] = w1;
            out_w[row * 2 + 1] = 1.0f - w1;
        }

        float m = lgt;
#pragma unroll
        for (int ss = 32; ss >= 1; ss >>= 1) m = fmaxf(m, __shfl_xor(m, ss));
        const float p = expf(lgt - m);
        float sum = p;
#pragma unroll
        for (int ss = 32; ss >= 1; ss >>= 1) sum += __shfl_xor(sum, ss);
        psum_local += p / sum;
        cnt_local += (lane == i1 ? 1.f : 0.f) + (lane == i2 ? 1.f : 0.f);
    }

    sps[w][lane] = psum_local;
    scnt[w][lane] = cnt_local;
    __syncthreads();
    if (t < 64) {
        float ssum = 0.f, c = 0.f;
#pragma unroll
        for (int ww = 0; ww < 4; ++ww) { ssum += sps[ww][t]; c += scnt[ww][t]; }
        atomicAdd(&probsum[t], ssum);
        atomicAdd(&counts[t], c);
    }
    __syncthreads();
    if (t == 0) {
        __threadfence();
        lastFlag = (atomicAdd(done, 1) == (int)gridDim.x - 1) ? 1 : 0;
    }
    __syncthreads();
    if (lastFlag && t < 64) {
        const float ps = __hip_atomic_load(&probsum[t], __ATOMIC_RELAXED,
                                           __HIP_MEMORY_SCOPE_AGENT);
        const float ct = __hip_atomic_load(&counts[t], __ATOMIC_RELAXED,
                                           __HIP_MEMORY_SCOPE_AGENT);
        float v = ps * ct;
#pragma unroll
        for (int ss = 32; ss >= 1; ss >>= 1) v += __shfl_xor(v, ss);
        if (t == 0)
            out[557056] = (float)NEXP * v / ((float)BATCH * (float)BATCH);
    }
}

// ============================================================================
// 3-dispatch pipeline: build_wf(+zero), gemm, router(+loss).
// ============================================================================
extern "C" void kernel_launch(void* const* d_in, const int* in_sizes, int n_in,
                              void* d_out, int out_size, void* d_ws, size_t ws_size,
                              hipStream_t stream)
{
    const float* x = (const float*)d_in[0];
    const float* W = (const float*)d_in[1];
    const float* noise = (const float*)d_in[2];
    float* out = (float*)d_out;
    float* ws = (float*)d_ws;

    float* probsum = ws;                                   // 64 floats
    float* counts = ws + 64;                               // 64 floats
    int* done = (int*)(ws + 128);                          // 1 int
    unsigned short* WF2 = (unsigned short*)(ws + 512);     // 1.5 MB
    float* part = ws + 512 + WF_FLOATS;                    // S * 8192 * 64 floats

    int S = 1;
    const size_t base_floats = 512 + WF_FLOATS;
    for (int cand = 8; cand >= 1; cand >>= 1) {
        const size_t need = (base_floats + (size_t)cand * BATCH * NEXP) * sizeof(float);
        if (ws_size >= need) { S = cand; break; }
    }

    build_wf<<<128, 256, 0, stream>>>(W, WF2, ws);
    gemm_mfma<<<128 * S, 256, 0, stream>>>(x, WF2, part, S);
    switch (S) {
        case 8: router2<8><<<256, 256, 0, stream>>>(part, noise, out, probsum, counts, done); break;
        case 4: router2<4><<<256, 256, 0, stream>>>(part, noise, out, probsum, counts, done); break;
        case 2: router2<2><<<256, 256, 0, stream>>>(part, noise, out, probsum, counts, done); break;
        default: router2<1><<<256, 256, 0, stream>>>(part, noise, out, probsum, counts, done); break;
    }
}